// Round 1
// baseline (16154.266 us; speedup 1.0000x reference)
//
#include <hip/hip_runtime.h>
#include <math.h>

// SpikingModel: 500-step EIF recurrent net, B=16, N=4096, fp32.
// Per step: Z = Y @ W^T + x0 ; EIF update ; spike ; trace decay.
//
// ws layout (floats):
//   Yt  [N][B]     @ 0        (65536)  -- Y transposed for wave-uniform scalar loads
//   V   [B][N]     @ 65536
//   r   [B][N]     @ 131072
//   zp  [4][B][N]  @ 196608   (262144) -- K-split partial sums
// total 458752 floats = 1.75 MB

#define NN 4096
#define NB 65536
#define YT_OFF 0
#define V_OFF  65536
#define R_OFF  131072
#define ZP_OFF 196608

__global__ __launch_bounds__(1024) void init_kernel(const float* __restrict__ V0,
                                                    const float* __restrict__ Y0,
                                                    float* __restrict__ ws) {
    int gid = blockIdx.x * 1024 + threadIdx.x;   // 64 blocks x 1024
    int b = gid >> 12, i = gid & 4095;
    ws[V_OFF + gid] = V0[gid];
    ws[R_OFF + gid] = 0.0f;
    ws[YT_OFF + i * 16 + b] = Y0[gid];           // transpose Y0 (zeros, but honor input)
}

// grid 256 blocks x 1024 threads. Block g: rows [R0, R0+64), col-group c (1024 cols).
// Wave w: 64-col subchunk; lane l: row R0+l. Y read via wave-uniform addresses
// (scalar-load path); W read as float4 per lane (stride-16KB across lanes, but
// 4 successive float4 of a row share a 64B line -> L1 reuse).
__global__ __launch_bounds__(1024) void matmul_kernel(const float* __restrict__ W,
                                                      const float* __restrict__ Yt,
                                                      float* __restrict__ zp) {
    __shared__ float red[16 * 16 * 64];          // [w][b][lane] = 64 KB
    int g = blockIdx.x;
    int R0 = (g >> 2) << 6;
    int c = g & 3;
    int w = __builtin_amdgcn_readfirstlane((int)(threadIdx.x >> 6));
    int lane = threadIdx.x & 63;
    int row = R0 + lane;
    int k0 = (c << 10) + (w << 6);
    const float4* Wp = (const float4*)(W + (size_t)row * NN + k0);
    const float*  Yp = Yt + k0 * 16;

    float acc[16];
#pragma unroll
    for (int b = 0; b < 16; ++b) acc[b] = 0.0f;

#pragma unroll
    for (int kk = 0; kk < 16; ++kk) {
        float4 wv = Wp[kk];
        const float* y = Yp + (kk << 6);         // 4 k-rows of Yt, 16 floats each
#pragma unroll
        for (int b = 0; b < 16; ++b) acc[b] = fmaf(wv.x, y[b],      acc[b]);
#pragma unroll
        for (int b = 0; b < 16; ++b) acc[b] = fmaf(wv.y, y[16 + b], acc[b]);
#pragma unroll
        for (int b = 0; b < 16; ++b) acc[b] = fmaf(wv.z, y[32 + b], acc[b]);
#pragma unroll
        for (int b = 0; b < 16; ++b) acc[b] = fmaf(wv.w, y[48 + b], acc[b]);
    }

    // intra-block reduction across the 16 wave k-chunks
    int wbase = ((int)(threadIdx.x >> 6)) << 10;
#pragma unroll
    for (int b = 0; b < 16; ++b) red[wbase + (b << 6) + lane] = acc[b];
    __syncthreads();

    int b2 = threadIdx.x >> 6;
    int l2 = threadIdx.x & 63;
    float s = 0.0f;
#pragma unroll
    for (int w2 = 0; w2 < 16; ++w2) s += red[(w2 << 10) + (b2 << 6) + l2];
    zp[(c << 16) + (b2 << 12) + R0 + l2] = s;    // coalesced
}

__global__ __launch_bounds__(1024) void update_kernel(const float* __restrict__ x0,
                                                      float* __restrict__ ws) {
    int gid = blockIdx.x * 1024 + threadIdx.x;   // 64 blocks x 1024
    int b = gid >> 12, i = gid & 4095;
    const float* zp = ws + ZP_OFF;
    float z = zp[gid] + zp[NB + gid] + zp[2 * NB + gid] + zp[3 * NB + gid] + x0[gid];
    float v = ws[V_OFF + gid];
    float y = ws[YT_OFF + i * 16 + b];

    // dV = (-(V-EL) + DT_EIF*exp((V-VT_)/DT_EIF) + Z) / TAUM ; EL=-72, VT_=-55, TAUM=10
    float ex = expf(v + 55.0f);
    float dV = (-(v + 72.0f) + ex + z) / 10.0f;
    v = fmaxf(v + 0.1f * dV, -85.0f);            // Euler step + lower clamp (VLB=-85)
    bool sp = (v >= 0.0f);                       // VTH = 0
    float S = sp ? 10.0f : 0.0f;                 // inv_dt = 10
    if (sp) v = -72.0f;                          // reset to VRE
    y = y + 0.0125f * (S - y);                   // dt/TAUSYN = 0.1/8

    ws[V_OFF + gid] = v;
    ws[YT_OFF + i * 16 + b] = y;
    ws[R_OFF + gid] += S;
}

__global__ __launch_bounds__(1024) void final_kernel(const float* __restrict__ r,
                                                     float* __restrict__ out) {
    int gid = blockIdx.x * 1024 + threadIdx.x;
    out[gid] = r[gid] * 0.002f;                  // dt/T = 0.1/50
}

extern "C" void kernel_launch(void* const* d_in, const int* in_sizes, int n_in,
                              void* d_out, int out_size, void* d_ws, size_t ws_size,
                              hipStream_t stream) {
    const float* W  = (const float*)d_in[0];
    const float* x0 = (const float*)d_in[1];
    const float* V0 = (const float*)d_in[2];
    const float* Y0 = (const float*)d_in[3];
    float* out = (float*)d_out;
    float* ws  = (float*)d_ws;

    init_kernel<<<64, 1024, 0, stream>>>(V0, Y0, ws);
    for (int t = 0; t < 500; ++t) {
        matmul_kernel<<<256, 1024, 0, stream>>>(W, ws + YT_OFF, ws + ZP_OFF);
        update_kernel<<<64, 1024, 0, stream>>>(x0, ws);
    }
    final_kernel<<<64, 1024, 0, stream>>>(ws + R_OFF, out);
}

// Round 2
// 13688.394 us; speedup vs baseline: 1.1801x; 1.1801x over previous
//
#include <hip/hip_runtime.h>
#include <math.h>

// SpikingModel: 500-step EIF recurrent net, B=16, N=4096, fp32.
// One fused kernel per step: Z = Y @ W^T + x0 ; EIF update ; trace decay.
//
// Step kernel: grid 256 x 512 thr. Block owns n in [R0, R0+16).
//   8 waves = 4 k-groups x 2 n-groups; lane-tile = 8n x 16b (128 accs).
//   Lanes span k (one float4 each) -> W global loads coalesced (1KB/instr),
//   Y read from LDS as dense contiguous ds_read_b128.
//   Cross-lane k-reduction: halving butterfly (63 shuffles per 64-set).
//   Cross-kg reduction + neuron update: LDS zred + 256 update threads.
//
// ws layout (floats): Ya[16][4096] @0, Yb @65536, V @131072, r @196608.

#define NN 4096
#define YA_OFF 0
#define YB_OFF 65536
#define V_OFF  131072
#define R_OFF  196608

#define GAS __attribute__((address_space(1)))
#define LAS __attribute__((address_space(3)))

__global__ __launch_bounds__(512) void init_kernel(const float* __restrict__ V0,
                                                   const float* __restrict__ Y0,
                                                   float* __restrict__ ws) {
    int gid = blockIdx.x * 512 + threadIdx.x;    // 128 blocks x 512 = 65536
    ws[V_OFF + gid] = V0[gid];
    ws[R_OFF + gid] = 0.0f;
    ws[YA_OFF + gid] = Y0[gid];
}

// Halving butterfly over a 64-float register set: on return v[BASE] holds the
// 64-lane sum of original v[BASE + lane]. Proof of mapping: stage mask m keeps
// index bit m equal to lane bit m, compacted; final slot0 <-> j = lane.
template<int BASE>
__device__ __forceinline__ void butterfly64(float (&v)[128], int lane) {
#pragma unroll
    for (int m = 1; m <= 32; m <<= 1) {
        const int live = 64 / m;
#pragma unroll
        for (int i = 0; i < live / 2; ++i) {
            float a = v[BASE + 2 * i], b = v[BASE + 2 * i + 1];
            float send = (lane & m) ? a : b;
            float keep = (lane & m) ? b : a;
            float recv = __shfl_xor(send, m, 64);
            v[BASE + i] = keep + recv;
        }
    }
}

__global__ __launch_bounds__(512, 2) void step_kernel(const float* __restrict__ W,
                                                      const float* __restrict__ x0,
                                                      const float* __restrict__ Yin,
                                                      float* __restrict__ Yout,
                                                      float* __restrict__ V,
                                                      float* __restrict__ r) {
    __shared__ float lds[16384];                 // 64 KB: Y-stage chunk, then zred alias
    const int R0 = blockIdx.x * 16;
    const int t = threadIdx.x;
    const int w = t >> 6;                        // wave 0..7
    const int lane = t & 63;
    const int kg = w >> 1;                       // k-group 0..3 (256-k sub per chunk)
    const int ng = w & 1;                        // n-group 0..1 (8 n each)

    float acc[128];                              // [nn][b] = acc[nn*16+b]
#pragma unroll
    for (int i = 0; i < 128; ++i) acc[i] = 0.0f;

    const int koff = kg * 256 + 4 * lane;        // lane's float4 position in chunk

#pragma unroll 1
    for (int c = 0; c < 4; ++c) {                // 4 chunks of 1024 k
        const int k0 = c * 1024;
        // stage Y[b][k0..k0+1024) -> lds[b*1024 + .] via async global->LDS, 16B/lane
#pragma unroll
        for (int i = 0; i < 8; ++i) {
            int f = i * 512 + t;                 // float4 index in chunk
            int b = f >> 8;                      // 256 float4 per b-row
            int pos = (f & 255) * 4;             // float offset in row
            __builtin_amdgcn_global_load_lds(
                (const GAS void*)(Yin + (size_t)b * NN + k0 + pos),
                (LAS void*)(&lds[b * 1024 + pos]), 16, 0, 0);
        }
        __syncthreads();

        // compute: 8 W rows (coalesced) x 16 b (dense LDS) x 4 k
        const float* Wbase = W + (size_t)(R0 + ng * 8) * NN + k0 + koff;
        float4 wv[8];
#pragma unroll
        for (int nn = 0; nn < 8; ++nn)
            wv[nn] = *(const float4*)(Wbase + (size_t)nn * NN);
#pragma unroll
        for (int b = 0; b < 16; ++b) {
            float4 yv = *(const float4*)(&lds[b * 1024 + koff]);
#pragma unroll
            for (int nn = 0; nn < 8; ++nn) {
                float s = acc[nn * 16 + b];
                s = fmaf(wv[nn].x, yv.x, s);
                s = fmaf(wv[nn].y, yv.y, s);
                s = fmaf(wv[nn].z, yv.z, s);
                s = fmaf(wv[nn].w, yv.w, s);
                acc[nn * 16 + b] = s;
            }
        }
        __syncthreads();
    }

    // in-wave k-reduction: two 64-sets -> lane holds totals for
    // (nn = h*4 + (lane>>4), b = lane&15), h = 0,1
    butterfly64<0>(acc, lane);
    butterfly64<64>(acc, lane);

    // cross-kg reduction via LDS (aliases Y-stage; safe after last barrier)
    lds[(w * 2 + 0) * 64 + lane] = acc[0];
    lds[(w * 2 + 1) * 64 + lane] = acc[64];
    __syncthreads();

    if (t < 256) {                               // one thread per (b, n_local)
        const int b = t >> 4;
        const int nl = t & 15;
        const int n = R0 + nl;
        const int ng2 = nl >> 3;
        const int nn = nl & 7;
        const int h = nn >> 2;
        const int li = (nn & 3) * 16 + b;
        float z = 0.0f;
#pragma unroll
        for (int kg2 = 0; kg2 < 4; ++kg2)
            z += lds[(((kg2 * 2 + ng2) * 2) + h) * 64 + li];

        const int gid = b * NN + n;
        z += x0[gid];
        float v = V[gid];
        float y = Yin[gid];

        // EIF: dV = (-(V-EL) + DT*exp((V-VT)/DT) + Z)/TAUM; EL=-72 VT=-55 TAUM=10
        float ex = expf(v + 55.0f);
        float dV = (-(v + 72.0f) + ex + z) / 10.0f;
        v = fmaxf(v + 0.1f * dV, -85.0f);        // Euler + clamp VLB=-85
        bool sp = (v >= 0.0f);                   // VTH=0
        float S = sp ? 10.0f : 0.0f;             // inv_dt
        if (sp) v = -72.0f;                      // reset VRE
        y = y + 0.0125f * (S - y);               // dt/TAUSYN

        V[gid] = v;
        Yout[gid] = y;
        r[gid] += S;
    }
}

__global__ __launch_bounds__(512) void final_kernel(const float* __restrict__ r,
                                                    float* __restrict__ out) {
    int gid = blockIdx.x * 512 + threadIdx.x;
    out[gid] = r[gid] * 0.002f;                  // dt/T
}

extern "C" void kernel_launch(void* const* d_in, const int* in_sizes, int n_in,
                              void* d_out, int out_size, void* d_ws, size_t ws_size,
                              hipStream_t stream) {
    const float* W  = (const float*)d_in[0];
    const float* x0 = (const float*)d_in[1];
    const float* V0 = (const float*)d_in[2];
    const float* Y0 = (const float*)d_in[3];
    float* out = (float*)d_out;
    float* ws  = (float*)d_ws;

    float* Ya = ws + YA_OFF;
    float* Yb = ws + YB_OFF;
    float* V  = ws + V_OFF;
    float* r  = ws + R_OFF;

    init_kernel<<<128, 512, 0, stream>>>(V0, Y0, ws);
    for (int t = 0; t < 500; ++t) {
        const float* Yin = (t & 1) ? Yb : Ya;
        float* Yout      = (t & 1) ? Ya : Yb;
        step_kernel<<<256, 512, 0, stream>>>(W, x0, Yin, Yout, V, r);
    }
    final_kernel<<<128, 512, 0, stream>>>(r, out);
}

// Round 3
// 566.052 us; speedup vs baseline: 28.5385x; 24.1822x over previous
//
#include <hip/hip_runtime.h>
#include <math.h>

// SpikingModel: 500-step EIF recurrent net, B=16, N=4096, fp32.
// Event-driven formulation: maintain Zrec = Y @ W^T incrementally.
//   Zrec(t+1) = 0.9875*Zrec(t) + 0.125 * sum_{spikes (b,j)} W[:,j]   (row b only)
// Spike (b,j) affects only batch row b -> one block per row -> all
// communication is intra-block __syncthreads(). Whole recurrence = 1 kernel.
// Dense matmul runs ONCE for Zrec(0) = Y0 @ W^T (round-2 validated structure).
//
// ws layout (floats): Zrec[16][4096] @ 0  (65536 floats)

#define NN 4096

#define GAS __attribute__((address_space(1)))
#define LAS __attribute__((address_space(3)))

// ---------- one-time dense matmul: Zrec = Y0 @ W^T (r2 structure) ----------

template<int BASE>
__device__ __forceinline__ void butterfly64(float (&v)[128], int lane) {
#pragma unroll
    for (int m = 1; m <= 32; m <<= 1) {
        const int live = 64 / m;
#pragma unroll
        for (int i = 0; i < live / 2; ++i) {
            float a = v[BASE + 2 * i], b = v[BASE + 2 * i + 1];
            float send = (lane & m) ? a : b;
            float keep = (lane & m) ? b : a;
            float recv = __shfl_xor(send, m, 64);
            v[BASE + i] = keep + recv;
        }
    }
}

__global__ __launch_bounds__(512, 2) void zrec_kernel(const float* __restrict__ W,
                                                      const float* __restrict__ Y0,
                                                      float* __restrict__ zrec) {
    __shared__ float lds[16384];
    const int R0 = blockIdx.x * 16;
    const int t = threadIdx.x;
    const int w = t >> 6;
    const int lane = t & 63;
    const int kg = w >> 1;
    const int ng = w & 1;

    float acc[128];
#pragma unroll
    for (int i = 0; i < 128; ++i) acc[i] = 0.0f;

    const int koff = kg * 256 + 4 * lane;

#pragma unroll 1
    for (int c = 0; c < 4; ++c) {
        const int k0 = c * 1024;
#pragma unroll
        for (int i = 0; i < 8; ++i) {
            int f = i * 512 + t;
            int b = f >> 8;
            int pos = (f & 255) * 4;
            __builtin_amdgcn_global_load_lds(
                (const GAS void*)(Y0 + (size_t)b * NN + k0 + pos),
                (LAS void*)(&lds[b * 1024 + pos]), 16, 0, 0);
        }
        __syncthreads();

        const float* Wbase = W + (size_t)(R0 + ng * 8) * NN + k0 + koff;
        float4 wv[8];
#pragma unroll
        for (int nn = 0; nn < 8; ++nn)
            wv[nn] = *(const float4*)(Wbase + (size_t)nn * NN);
#pragma unroll
        for (int b = 0; b < 16; ++b) {
            float4 yv = *(const float4*)(&lds[b * 1024 + koff]);
#pragma unroll
            for (int nn = 0; nn < 8; ++nn) {
                float s = acc[nn * 16 + b];
                s = fmaf(wv[nn].x, yv.x, s);
                s = fmaf(wv[nn].y, yv.y, s);
                s = fmaf(wv[nn].z, yv.z, s);
                s = fmaf(wv[nn].w, yv.w, s);
                acc[nn * 16 + b] = s;
            }
        }
        __syncthreads();
    }

    butterfly64<0>(acc, lane);
    butterfly64<64>(acc, lane);

    lds[(w * 2 + 0) * 64 + lane] = acc[0];
    lds[(w * 2 + 1) * 64 + lane] = acc[64];
    __syncthreads();

    if (t < 256) {
        const int b = t >> 4;
        const int nl = t & 15;
        const int ng2 = nl >> 3;
        const int nn = nl & 7;
        const int h = nn >> 2;
        const int li = (nn & 3) * 16 + b;
        float z = 0.0f;
#pragma unroll
        for (int kg2 = 0; kg2 < 4; ++kg2)
            z += lds[(((kg2 * 2 + ng2) * 2) + h) * 64 + li];
        zrec[b * NN + R0 + nl] = z;
    }
}

// ---------- persistent event-driven kernel: 500 steps, 1 block per row ----------

__global__ __launch_bounds__(1024) void persist_kernel(const float* __restrict__ W,
                                                       const float* __restrict__ x0,
                                                       const float* __restrict__ V0,
                                                       float* __restrict__ zrec,
                                                       float* __restrict__ out) {
    __shared__ unsigned long long masks[2][16];  // per-wave "any spike" ballots
    __shared__ int cnt;                          // slow-path spike count
    __shared__ int list[4096];                   // slow-path spike neuron indices

    const int b = blockIdx.x;                    // 16 blocks = 16 batch rows
    const int t = threadIdx.x;                   // 1024 threads, 4 neurons each
    const int wv = t >> 6;
    const int lane = t & 63;
    const int n0 = t * 4;
    const size_t base = (size_t)b * NN + n0;

    float4 zr = *(const float4*)(zrec + base);   // Zrec(0) = Y0@W^T
    float4 v  = *(const float4*)(V0 + base);
    float4 xx = *(const float4*)(x0 + base);
    float4 r  = {0.0f, 0.0f, 0.0f, 0.0f};

#pragma unroll 1
    for (int step = 0; step < 500; ++step) {
        const int p = step & 1;

        // ---- neuron update (EIF), spike detect, trace-equivalent decay ----
        // dV = (-(V+72) + exp(V+55) + Z)/10 ; V += 0.1*dV ; clamp -85 ;
        // spike at V>=0 -> S=10, V=-72 ; Zrec *= (1 - dt/tausyn) = 0.9875
        float z0 = zr.x + xx.x, z1 = zr.y + xx.y, z2 = zr.z + xx.z, z3 = zr.w + xx.w;

        float e0 = expf(v.x + 55.0f), e1 = expf(v.y + 55.0f);
        float e2 = expf(v.z + 55.0f), e3 = expf(v.w + 55.0f);
        v.x = fmaxf(fmaf(0.01f, -(v.x + 72.0f) + e0 + z0, v.x), -85.0f);
        v.y = fmaxf(fmaf(0.01f, -(v.y + 72.0f) + e1 + z1, v.y), -85.0f);
        v.z = fmaxf(fmaf(0.01f, -(v.z + 72.0f) + e2 + z2, v.z), -85.0f);
        v.w = fmaxf(fmaf(0.01f, -(v.w + 72.0f) + e3 + z3, v.w), -85.0f);

        bool s0 = v.x >= 0.0f, s1 = v.y >= 0.0f, s2 = v.z >= 0.0f, s3 = v.w >= 0.0f;
        if (s0) { v.x = -72.0f; r.x += 10.0f; }
        if (s1) { v.y = -72.0f; r.y += 10.0f; }
        if (s2) { v.z = -72.0f; r.z += 10.0f; }
        if (s3) { v.w = -72.0f; r.w += 10.0f; }

        zr.x *= 0.9875f; zr.y *= 0.9875f; zr.z *= 0.9875f; zr.w *= 0.9875f;

        // ---- spike exchange: per-wave ballot, full overwrite (no clears) ----
        bool any = s0 | s1 | s2 | s3;
        unsigned long long bal = __ballot(any);
        if (lane == 0) masks[p][wv] = bal;
        __syncthreads();

        unsigned long long tot = 0;
#pragma unroll
        for (int i = 0; i < 16; ++i) tot |= masks[p][i];

        if (tot != 0) {                          // slow path: block-uniform entry
            if (t == 0) cnt = 0;
            __syncthreads();
            int k = (int)s0 + (int)s1 + (int)s2 + (int)s3;
            if (k) {
                int pos = atomicAdd(&cnt, k);
                if (s0) list[pos++] = n0 + 0;
                if (s1) list[pos++] = n0 + 1;
                if (s2) list[pos++] = n0 + 2;
                if (s3) list[pos++] = n0 + 3;
            }
            __syncthreads();
            int m = cnt;
            for (int s = 0; s < m; ++s) {
                int j = list[s];                 // Zrec[b,n] += 0.125*W[n,j]
                zr.x += 0.125f * W[(size_t)(n0 + 0) * NN + j];
                zr.y += 0.125f * W[(size_t)(n0 + 1) * NN + j];
                zr.z += 0.125f * W[(size_t)(n0 + 2) * NN + j];
                zr.w += 0.125f * W[(size_t)(n0 + 3) * NN + j];
            }
        }
    }

    // out = r * dt/T = r * 0.002
    float4 o = {r.x * 0.002f, r.y * 0.002f, r.z * 0.002f, r.w * 0.002f};
    *(float4*)(out + base) = o;
}

extern "C" void kernel_launch(void* const* d_in, const int* in_sizes, int n_in,
                              void* d_out, int out_size, void* d_ws, size_t ws_size,
                              hipStream_t stream) {
    const float* W  = (const float*)d_in[0];
    const float* x0 = (const float*)d_in[1];
    const float* V0 = (const float*)d_in[2];
    const float* Y0 = (const float*)d_in[3];
    float* out  = (float*)d_out;
    float* zrec = (float*)d_ws;

    zrec_kernel<<<256, 512, 0, stream>>>(W, Y0, zrec);
    persist_kernel<<<16, 1024, 0, stream>>>(W, x0, V0, zrec, out);
}

// Round 4
// 134.860 us; speedup vs baseline: 119.7857x; 4.1973x over previous
//
#include <hip/hip_runtime.h>
#include <math.h>

// SpikingModel: 500-step EIF recurrent net, B=16, N=4096, fp32.
// Round-4 structure: speculative no-spike fast path + event-driven fallback.
//
// Neurons couple ONLY via spikes. Speculative kernel integrates every neuron
// independently (no barriers, all 256 CUs); if its trajectory shows no spike,
// the true trajectory is identical (spec == truth up to the first spike) and
// out = r*dt/T = 0 exactly. Spike flags gate the r3 event-driven persistent
// fallback (correct for arbitrary spiking). Zrec(0) = Y0@W^T is gated on
// Y0 != 0 (Y0 is zeros here -> zero-fill, skip 64MB W sweep).
//
// ws layout: zrec[16][4096] floats @ 0 ; yflags[64] ints @ float-off 65536 ;
//            sflags[256] ints @ float-off 65600.

#define NN 4096

#define GAS __attribute__((address_space(1)))
#define LAS __attribute__((address_space(3)))

// ---------------- Y0 nonzero scan (always-written per-block slots) ----------

__global__ __launch_bounds__(1024) void yscan_kernel(const float* __restrict__ Y0,
                                                     int* __restrict__ yflags) {
    __shared__ unsigned long long m[16];
    const int t = threadIdx.x;
    const int gid = blockIdx.x * 1024 + t;      // 64 blocks x 1024
    bool nz = Y0[gid] != 0.0f;
    unsigned long long bal = __ballot(nz);
    if ((t & 63) == 0) m[t >> 6] = bal;
    __syncthreads();
    if (t == 0) {
        unsigned long long tot = 0;
#pragma unroll
        for (int i = 0; i < 16; ++i) tot |= m[i];
        yflags[blockIdx.x] = tot ? 1 : 0;
    }
}

// ---------------- one-time dense Zrec(0) = Y0@W^T, gated on yflags ----------

template<int BASE>
__device__ __forceinline__ void butterfly64(float (&v)[128], int lane) {
#pragma unroll
    for (int m = 1; m <= 32; m <<= 1) {
        const int live = 64 / m;
#pragma unroll
        for (int i = 0; i < live / 2; ++i) {
            float a = v[BASE + 2 * i], b = v[BASE + 2 * i + 1];
            float send = (lane & m) ? a : b;
            float keep = (lane & m) ? b : a;
            float recv = __shfl_xor(send, m, 64);
            v[BASE + i] = keep + recv;
        }
    }
}

__global__ __launch_bounds__(512, 2) void zrec_kernel(const float* __restrict__ W,
                                                      const float* __restrict__ Y0,
                                                      const int* __restrict__ yflags,
                                                      float* __restrict__ zrec) {
    __shared__ float lds[16384];
    const int R0 = blockIdx.x * 16;
    const int t = threadIdx.x;
    const int lane = t & 63;

    // gate: if Y0 == 0 everywhere, Zrec(0) = 0 -- skip the 64MB W sweep
    bool ynz = yflags[lane] != 0;               // 64 slots, one per lane
    if (!__any(ynz)) {
        if (t < 256) zrec[(t >> 4) * NN + R0 + (t & 15)] = 0.0f;
        return;                                  // uniform: before any barrier
    }

    const int w = t >> 6;
    const int kg = w >> 1;
    const int ng = w & 1;

    float acc[128];
#pragma unroll
    for (int i = 0; i < 128; ++i) acc[i] = 0.0f;

    const int koff = kg * 256 + 4 * lane;

#pragma unroll 1
    for (int c = 0; c < 4; ++c) {
        const int k0 = c * 1024;
#pragma unroll
        for (int i = 0; i < 8; ++i) {
            int f = i * 512 + t;
            int b = f >> 8;
            int pos = (f & 255) * 4;
            __builtin_amdgcn_global_load_lds(
                (const GAS void*)(Y0 + (size_t)b * NN + k0 + pos),
                (LAS void*)(&lds[b * 1024 + pos]), 16, 0, 0);
        }
        __syncthreads();

        const float* Wbase = W + (size_t)(R0 + ng * 8) * NN + k0 + koff;
        float4 wv[8];
#pragma unroll
        for (int nn = 0; nn < 8; ++nn)
            wv[nn] = *(const float4*)(Wbase + (size_t)nn * NN);
#pragma unroll
        for (int b = 0; b < 16; ++b) {
            float4 yv = *(const float4*)(&lds[b * 1024 + koff]);
#pragma unroll
            for (int nn = 0; nn < 8; ++nn) {
                float s = acc[nn * 16 + b];
                s = fmaf(wv[nn].x, yv.x, s);
                s = fmaf(wv[nn].y, yv.y, s);
                s = fmaf(wv[nn].z, yv.z, s);
                s = fmaf(wv[nn].w, yv.w, s);
                acc[nn * 16 + b] = s;
            }
        }
        __syncthreads();
    }

    butterfly64<0>(acc, lane);
    butterfly64<64>(acc, lane);

    lds[(w * 2 + 0) * 64 + lane] = acc[0];
    lds[(w * 2 + 1) * 64 + lane] = acc[64];
    __syncthreads();

    if (t < 256) {
        const int b = t >> 4;
        const int nl = t & 15;
        const int ng2 = nl >> 3;
        const int nn = nl & 7;
        const int h = nn >> 2;
        const int li = (nn & 3) * 16 + b;
        float z = 0.0f;
#pragma unroll
        for (int kg2 = 0; kg2 < 4; ++kg2)
            z += lds[(((kg2 * 2 + ng2) * 2) + h) * 64 + li];
        zrec[b * NN + R0 + nl] = z;
    }
}

// ---------------- speculative no-spike integrator: no barriers -------------

__global__ __launch_bounds__(256) void spec_kernel(const float* __restrict__ x0,
                                                   const float* __restrict__ V0,
                                                   const float* __restrict__ zrec,
                                                   int* __restrict__ sflags,
                                                   float* __restrict__ out) {
    __shared__ unsigned long long m[4];
    const int t = threadIdx.x;
    const int gid = blockIdx.x * 256 + t;        // 256 blocks x 256 = 65536
    float z = zrec[gid];                         // recurrent drive, decays 0.9875/step
    float v = V0[gid];
    const float x = x0[gid];
    bool spiked = false;

#pragma unroll 1
    for (int s = 0; s < 500; ++s) {
        float e = __expf(v + 55.0f);
        v = fmaxf(fmaf(0.01f, -(v + 72.0f) + e + z + x, v), -85.0f);
        if (v >= 0.0f) { spiked = true; break; } // first spike = genuine spike
        z *= 0.9875f;
    }

    // per-block spike slot: ALWAYS written (re-poison-safe, no init needed)
    unsigned long long bal = __ballot(spiked);
    if ((t & 63) == 0) m[t >> 6] = bal;
    __syncthreads();
    if (t == 0) sflags[blockIdx.x] = (m[0] | m[1] | m[2] | m[3]) ? 1ull : 0ull;

    // no spike anywhere => r == 0 => out == 0 exactly (overwritten by fallback
    // if any block saw a spike)
    out[gid] = 0.0f;
}

// ---------------- event-driven fallback (r3, proven), gated on sflags ------

__global__ __launch_bounds__(1024) void persist_kernel(const float* __restrict__ W,
                                                       const float* __restrict__ x0,
                                                       const float* __restrict__ V0,
                                                       const int* __restrict__ sflags,
                                                       float* __restrict__ zrec,
                                                       float* __restrict__ out) {
    const int t = threadIdx.x;
    const int lane = t & 63;

    bool spk = false;
#pragma unroll
    for (int i = 0; i < 4; ++i) spk |= (sflags[lane + 64 * i] != 0);
    if (!__any(spk)) return;                     // uniform: before any barrier

    __shared__ unsigned long long masks[2][16];
    __shared__ int cnt;
    __shared__ int list[4096];

    const int b = blockIdx.x;
    const int wv = t >> 6;
    const int n0 = t * 4;
    const size_t base = (size_t)b * NN + n0;

    float4 zr = *(const float4*)(zrec + base);
    float4 v  = *(const float4*)(V0 + base);
    float4 xx = *(const float4*)(x0 + base);
    float4 r  = {0.0f, 0.0f, 0.0f, 0.0f};

#pragma unroll 1
    for (int step = 0; step < 500; ++step) {
        const int p = step & 1;

        float z0 = zr.x + xx.x, z1 = zr.y + xx.y, z2 = zr.z + xx.z, z3 = zr.w + xx.w;

        float e0 = expf(v.x + 55.0f), e1 = expf(v.y + 55.0f);
        float e2 = expf(v.z + 55.0f), e3 = expf(v.w + 55.0f);
        v.x = fmaxf(fmaf(0.01f, -(v.x + 72.0f) + e0 + z0, v.x), -85.0f);
        v.y = fmaxf(fmaf(0.01f, -(v.y + 72.0f) + e1 + z1, v.y), -85.0f);
        v.z = fmaxf(fmaf(0.01f, -(v.z + 72.0f) + e2 + z2, v.z), -85.0f);
        v.w = fmaxf(fmaf(0.01f, -(v.w + 72.0f) + e3 + z3, v.w), -85.0f);

        bool s0 = v.x >= 0.0f, s1 = v.y >= 0.0f, s2 = v.z >= 0.0f, s3 = v.w >= 0.0f;
        if (s0) { v.x = -72.0f; r.x += 10.0f; }
        if (s1) { v.y = -72.0f; r.y += 10.0f; }
        if (s2) { v.z = -72.0f; r.z += 10.0f; }
        if (s3) { v.w = -72.0f; r.w += 10.0f; }

        zr.x *= 0.9875f; zr.y *= 0.9875f; zr.z *= 0.9875f; zr.w *= 0.9875f;

        bool any = s0 | s1 | s2 | s3;
        unsigned long long bal = __ballot(any);
        if (lane == 0) masks[p][wv] = bal;
        __syncthreads();

        unsigned long long tot = 0;
#pragma unroll
        for (int i = 0; i < 16; ++i) tot |= masks[p][i];

        if (tot != 0) {
            if (t == 0) cnt = 0;
            __syncthreads();
            int k = (int)s0 + (int)s1 + (int)s2 + (int)s3;
            if (k) {
                int pos = atomicAdd(&cnt, k);
                if (s0) list[pos++] = n0 + 0;
                if (s1) list[pos++] = n0 + 1;
                if (s2) list[pos++] = n0 + 2;
                if (s3) list[pos++] = n0 + 3;
            }
            __syncthreads();
            int mcnt = cnt;
            for (int s = 0; s < mcnt; ++s) {
                int j = list[s];
                zr.x += 0.125f * W[(size_t)(n0 + 0) * NN + j];
                zr.y += 0.125f * W[(size_t)(n0 + 1) * NN + j];
                zr.z += 0.125f * W[(size_t)(n0 + 2) * NN + j];
                zr.w += 0.125f * W[(size_t)(n0 + 3) * NN + j];
            }
        }
    }

    float4 o = {r.x * 0.002f, r.y * 0.002f, r.z * 0.002f, r.w * 0.002f};
    *(float4*)(out + base) = o;
}

extern "C" void kernel_launch(void* const* d_in, const int* in_sizes, int n_in,
                              void* d_out, int out_size, void* d_ws, size_t ws_size,
                              hipStream_t stream) {
    const float* W  = (const float*)d_in[0];
    const float* x0 = (const float*)d_in[1];
    const float* V0 = (const float*)d_in[2];
    const float* Y0 = (const float*)d_in[3];
    float* out  = (float*)d_out;
    float* ws   = (float*)d_ws;

    float* zrec  = ws;                           // 65536 floats
    int* yflags  = (int*)(ws + 65536);           // 64 ints
    int* sflags  = (int*)(ws + 65600);           // 256 ints

    yscan_kernel<<<64, 1024, 0, stream>>>(Y0, yflags);
    zrec_kernel<<<256, 512, 0, stream>>>(W, Y0, yflags, zrec);
    spec_kernel<<<256, 256, 0, stream>>>(x0, V0, zrec, sflags, out);
    persist_kernel<<<16, 1024, 0, stream>>>(W, x0, V0, sflags, zrec, out);
}

// Round 5
// 110.717 us; speedup vs baseline: 145.9057x; 1.2181x over previous
//
#include <hip/hip_runtime.h>
#include <math.h>

// SpikingModel: 500-step EIF recurrent net, B=16, N=4096, fp32.
// Round-5: 3 dispatches.
//   zrec_kernel  : Zrec(0) = Y0@W^T, self-gated per 64KB chunk (bitwise OR scan
//                  of staged LDS + __syncthreads_or) -- Y0==0 => skip all FMA/W.
//   spec_kernel  : speculative barrier-free integrator, 4-op critical chain:
//                  fma -> v_exp -> fma -> max; spike detect via off-chain vmax.
//   persist_kernel: r3/r4-proven event-driven fallback, gated on spike flags.
//
// ws layout (floats): zrec[16][4096] @ 0 ; sflags[256] ints @ float-off 65536.

#define NN 4096

#define GAS __attribute__((address_space(1)))
#define LAS __attribute__((address_space(3)))

// ---------------- one-time dense Zrec(0) = Y0@W^T, chunk-self-gated ---------

template<int BASE>
__device__ __forceinline__ void butterfly64(float (&v)[128], int lane) {
#pragma unroll
    for (int m = 1; m <= 32; m <<= 1) {
        const int live = 64 / m;
#pragma unroll
        for (int i = 0; i < live / 2; ++i) {
            float a = v[BASE + 2 * i], b = v[BASE + 2 * i + 1];
            float send = (lane & m) ? a : b;
            float keep = (lane & m) ? b : a;
            float recv = __shfl_xor(send, m, 64);
            v[BASE + i] = keep + recv;
        }
    }
}

__global__ __launch_bounds__(512, 2) void zrec_kernel(const float* __restrict__ W,
                                                      const float* __restrict__ Y0,
                                                      float* __restrict__ zrec) {
    __shared__ float lds[16384];
    const int R0 = blockIdx.x * 16;
    const int t = threadIdx.x;
    const int w = t >> 6;
    const int lane = t & 63;
    const int kg = w >> 1;
    const int ng = w & 1;

    float acc[128];
#pragma unroll
    for (int i = 0; i < 128; ++i) acc[i] = 0.0f;

    const int koff = kg * 256 + 4 * lane;

#pragma unroll 1
    for (int c = 0; c < 4; ++c) {
        const int k0 = c * 1024;
        // stage Y0 chunk [16 b-rows x 1024 k] -> LDS, 16B async per lane
#pragma unroll
        for (int i = 0; i < 8; ++i) {
            int f = i * 512 + t;
            int b = f >> 8;
            int pos = (f & 255) * 4;
            __builtin_amdgcn_global_load_lds(
                (const GAS void*)(Y0 + (size_t)b * NN + k0 + pos),
                (LAS void*)(&lds[b * 1024 + pos]), 16, 0, 0);
        }
        __syncthreads();

        // chunk-zero scan: bitwise OR (conservative; -0.0 flags nonzero = safe)
        const int4* li4 = (const int4*)lds;
        int4 o = {0, 0, 0, 0};
#pragma unroll
        for (int i = 0; i < 8; ++i) {
            int4 q = li4[i * 512 + t];           // lanes consecutive: conflict-free
            o.x |= q.x; o.y |= q.y; o.z |= q.z; o.w |= q.w;
        }
        int nz = __syncthreads_or(o.x | o.y | o.z | o.w);

        if (nz) {
            const float* Wbase = W + (size_t)(R0 + ng * 8) * NN + k0 + koff;
            float4 wv[8];
#pragma unroll
            for (int nn = 0; nn < 8; ++nn)
                wv[nn] = *(const float4*)(Wbase + (size_t)nn * NN);
#pragma unroll
            for (int b = 0; b < 16; ++b) {
                float4 yv = *(const float4*)(&lds[b * 1024 + koff]);
#pragma unroll
                for (int nn = 0; nn < 8; ++nn) {
                    float s = acc[nn * 16 + b];
                    s = fmaf(wv[nn].x, yv.x, s);
                    s = fmaf(wv[nn].y, yv.y, s);
                    s = fmaf(wv[nn].z, yv.z, s);
                    s = fmaf(wv[nn].w, yv.w, s);
                    acc[nn * 16 + b] = s;
                }
            }
        }
        __syncthreads();
    }

    butterfly64<0>(acc, lane);
    butterfly64<64>(acc, lane);

    lds[(w * 2 + 0) * 64 + lane] = acc[0];
    lds[(w * 2 + 1) * 64 + lane] = acc[64];
    __syncthreads();

    if (t < 256) {
        const int b = t >> 4;
        const int nl = t & 15;
        const int ng2 = nl >> 3;
        const int nn = nl & 7;
        const int h = nn >> 2;
        const int li = (nn & 3) * 16 + b;
        float z = 0.0f;
#pragma unroll
        for (int kg2 = 0; kg2 < 4; ++kg2)
            z += lds[(((kg2 * 2 + ng2) * 2) + h) * 64 + li];
        zrec[b * NN + R0 + nl] = z;
    }
}

// ---------------- speculative integrator: 4-op critical chain --------------
// v' = max(0.99 v + 0.01 e^{v+55} + 0.01 z + 0.01 x - 0.72, -85)
// chain: fma(v,log2e,K) -> v_exp -> fma(0.01,e,w) -> max ; w,z,czt,vmax off-chain.
// Spike detect: vmax >= 0 at end. First genuine crossing is finite and latches
// vmax before any overflow (e overflows only at v>33, which implies v>=0 seen).

__global__ __launch_bounds__(256) void spec_kernel(const float* __restrict__ x0,
                                                   const float* __restrict__ V0,
                                                   const float* __restrict__ zrec,
                                                   int* __restrict__ sflags,
                                                   float* __restrict__ out) {
    __shared__ unsigned long long m[4];
    const int t = threadIdx.x;
    const int gid = blockIdx.x * 256 + t;        // 256 blocks x 256 = 65536
    float z = zrec[gid] * 0.01f;                 // pre-scaled recurrent drive
    float v = V0[gid];
    const float c = fmaf(0.01f, x0[gid], -0.72f);
    float czt = c + z;
    float vmax = v;
    const float L2E = 1.44269504088896f;
    const float K55 = 55.0f * 1.44269504088896f;

#pragma unroll 10
    for (int s = 0; s < 500; ++s) {
        float e = __builtin_amdgcn_exp2f(fmaf(v, L2E, K55));
        float w = fmaf(0.99f, v, czt);
        v = fmaxf(fmaf(0.01f, e, w), -85.0f);
        vmax = fmaxf(vmax, v);
        z *= 0.9875f;
        czt = c + z;
    }

    bool spiked = vmax >= 0.0f;
    unsigned long long bal = __ballot(spiked);
    if ((t & 63) == 0) m[t >> 6] = bal;
    __syncthreads();
    if (t == 0) sflags[blockIdx.x] = (m[0] | m[1] | m[2] | m[3]) ? 1 : 0;

    out[gid] = 0.0f;                             // overwritten by fallback if spikes
}

// ---------------- event-driven fallback (r3-proven), gated on sflags -------

__global__ __launch_bounds__(1024) void persist_kernel(const float* __restrict__ W,
                                                       const float* __restrict__ x0,
                                                       const float* __restrict__ V0,
                                                       const int* __restrict__ sflags,
                                                       float* __restrict__ zrec,
                                                       float* __restrict__ out) {
    const int t = threadIdx.x;
    const int lane = t & 63;

    bool spk = false;
#pragma unroll
    for (int i = 0; i < 4; ++i) spk |= (sflags[lane + 64 * i] != 0);
    if (!__any(spk)) return;                     // uniform exit: before any barrier

    __shared__ unsigned long long masks[2][16];
    __shared__ int cnt;
    __shared__ int list[4096];

    const int b = blockIdx.x;
    const int wv = t >> 6;
    const int n0 = t * 4;
    const size_t base = (size_t)b * NN + n0;

    float4 zr = *(const float4*)(zrec + base);
    float4 v  = *(const float4*)(V0 + base);
    float4 xx = *(const float4*)(x0 + base);
    float4 r  = {0.0f, 0.0f, 0.0f, 0.0f};

#pragma unroll 1
    for (int step = 0; step < 500; ++step) {
        const int p = step & 1;

        float z0 = zr.x + xx.x, z1 = zr.y + xx.y, z2 = zr.z + xx.z, z3 = zr.w + xx.w;

        float e0 = expf(v.x + 55.0f), e1 = expf(v.y + 55.0f);
        float e2 = expf(v.z + 55.0f), e3 = expf(v.w + 55.0f);
        v.x = fmaxf(fmaf(0.01f, -(v.x + 72.0f) + e0 + z0, v.x), -85.0f);
        v.y = fmaxf(fmaf(0.01f, -(v.y + 72.0f) + e1 + z1, v.y), -85.0f);
        v.z = fmaxf(fmaf(0.01f, -(v.z + 72.0f) + e2 + z2, v.z), -85.0f);
        v.w = fmaxf(fmaf(0.01f, -(v.w + 72.0f) + e3 + z3, v.w), -85.0f);

        bool s0 = v.x >= 0.0f, s1 = v.y >= 0.0f, s2 = v.z >= 0.0f, s3 = v.w >= 0.0f;
        if (s0) { v.x = -72.0f; r.x += 10.0f; }
        if (s1) { v.y = -72.0f; r.y += 10.0f; }
        if (s2) { v.z = -72.0f; r.z += 10.0f; }
        if (s3) { v.w = -72.0f; r.w += 10.0f; }

        zr.x *= 0.9875f; zr.y *= 0.9875f; zr.z *= 0.9875f; zr.w *= 0.9875f;

        bool any = s0 | s1 | s2 | s3;
        unsigned long long bal = __ballot(any);
        if (lane == 0) masks[p][wv] = bal;
        __syncthreads();

        unsigned long long tot = 0;
#pragma unroll
        for (int i = 0; i < 16; ++i) tot |= masks[p][i];

        if (tot != 0) {
            if (t == 0) cnt = 0;
            __syncthreads();
            int k = (int)s0 + (int)s1 + (int)s2 + (int)s3;
            if (k) {
                int pos = atomicAdd(&cnt, k);
                if (s0) list[pos++] = n0 + 0;
                if (s1) list[pos++] = n0 + 1;
                if (s2) list[pos++] = n0 + 2;
                if (s3) list[pos++] = n0 + 3;
            }
            __syncthreads();
            int mcnt = cnt;
            for (int s = 0; s < mcnt; ++s) {
                int j = list[s];
                zr.x += 0.125f * W[(size_t)(n0 + 0) * NN + j];
                zr.y += 0.125f * W[(size_t)(n0 + 1) * NN + j];
                zr.z += 0.125f * W[(size_t)(n0 + 2) * NN + j];
                zr.w += 0.125f * W[(size_t)(n0 + 3) * NN + j];
            }
        }
    }

    float4 o = {r.x * 0.002f, r.y * 0.002f, r.z * 0.002f, r.w * 0.002f};
    *(float4*)(out + base) = o;
}

extern "C" void kernel_launch(void* const* d_in, const int* in_sizes, int n_in,
                              void* d_out, int out_size, void* d_ws, size_t ws_size,
                              hipStream_t stream) {
    const float* W  = (const float*)d_in[0];
    const float* x0 = (const float*)d_in[1];
    const float* V0 = (const float*)d_in[2];
    const float* Y0 = (const float*)d_in[3];
    float* out  = (float*)d_out;
    float* ws   = (float*)d_ws;

    float* zrec = ws;                            // 65536 floats
    int* sflags = (int*)(ws + 65536);            // 256 ints

    zrec_kernel<<<256, 512, 0, stream>>>(W, Y0, zrec);
    spec_kernel<<<256, 256, 0, stream>>>(x0, V0, zrec, sflags, out);
    persist_kernel<<<16, 1024, 0, stream>>>(W, x0, V0, sflags, zrec, out);
}

// Round 6
// 101.908 us; speedup vs baseline: 158.5180x; 1.0864x over previous
//
#include <hip/hip_runtime.h>
#include <math.h>

// SpikingModel: 500-step EIF recurrent net, B=16, N=4096, fp32.
// Round-6: TWO dispatches.
//   spec_kernel   : per-block Y0-row zero-scan (one __syncthreads_or) ->
//                   z0 = 0 (common) or in-block dot(Y0[b,:], W[n,:]) (gated,
//                   structurally never taken: setup Y0 = zeros). Then the
//                   barrier-free 4-op-chain speculative integrator
//                   (fma -> v_exp -> fma -> max; off-chain vmax spike latch).
//                   Always writes z0 -> ws (for fallback) and spike flags.
//   persist_kernel: r3-proven event-driven fallback, gated on spike flags,
//                   uniform early-exit (~1 us) when no spikes anywhere.
//
// ws layout: zrec[16][4096] floats @ 0 ; sflags[256] ints @ float-off 65536.

#define NN 4096

// ---------------- speculative integrator + self-gated Zrec(0) ---------------

__global__ __launch_bounds__(256) void spec_kernel(const float* __restrict__ W,
                                                   const float* __restrict__ x0,
                                                   const float* __restrict__ V0,
                                                   const float* __restrict__ Y0,
                                                   float* __restrict__ zrec,
                                                   int* __restrict__ sflags,
                                                   float* __restrict__ out) {
    __shared__ float yrow[NN];                   // 16 KB row stage (fallback only)
    __shared__ unsigned long long m[4];
    const int t = threadIdx.x;
    const int gid = blockIdx.x * 256 + t;        // 256 blocks x 256 = 65536
    const int b = blockIdx.x >> 4;               // 16 blocks per batch row
    const int n = gid & (NN - 1);                // this thread's neuron

    // ---- Y0[b,:] zero-scan: 4 float4 per thread, bitwise OR (conservative) --
    const int4* Yr4 = (const int4*)(Y0 + (size_t)b * NN);
    int4 o = {0, 0, 0, 0};
#pragma unroll
    for (int i = 0; i < 4; ++i) {
        int4 q = Yr4[i * 256 + t];               // coalesced
        o.x |= q.x; o.y |= q.y; o.z |= q.z; o.w |= q.w;
    }
    int nz = __syncthreads_or(o.x | o.y | o.z | o.w);

    float z0 = 0.0f;
    if (nz) {                                    // gated dense fallback (never taken
        const float4* Yr = (const float4*)(Y0 + (size_t)b * NN);  //  for zero Y0)
#pragma unroll
        for (int i = 0; i < 4; ++i)
            ((float4*)yrow)[i * 256 + t] = Yr[i * 256 + t];
        __syncthreads();
        const float4* Wr = (const float4*)(W + (size_t)n * NN);
        float4 a = {0.0f, 0.0f, 0.0f, 0.0f};
        for (int k = 0; k < NN / 4; ++k) {
            float4 y = ((const float4*)yrow)[k];
            float4 w = Wr[k];
            a.x = fmaf(y.x, w.x, a.x);
            a.y = fmaf(y.y, w.y, a.y);
            a.z = fmaf(y.z, w.z, a.z);
            a.w = fmaf(y.w, w.w, a.w);
        }
        z0 = (a.x + a.y) + (a.z + a.w);
    }
    zrec[gid] = z0;                              // fallback's Zrec(0); always written

    // ---- 500-step integration, 4-op critical chain -------------------------
    // v' = max(0.99 v + 0.01 e^{v+55} + 0.01 z + 0.01 x - 0.72, -85)
    // chain: fma(v,log2e,K) -> v_exp -> fma(0.01,e,w) -> max; rest off-chain.
    // Spike detect: off-chain vmax latch (first genuine crossing is finite;
    // exp overflow needs v>33 which implies a prior v>=0).
    float z = z0 * 0.01f;
    float v = V0[gid];
    const float c = fmaf(0.01f, x0[gid], -0.72f);
    float czt = c + z;
    float vmax = v;
    const float L2E = 1.44269504088896f;
    const float K55 = 55.0f * 1.44269504088896f;

#pragma unroll 10
    for (int s = 0; s < 500; ++s) {
        float e = __builtin_amdgcn_exp2f(fmaf(v, L2E, K55));
        float w = fmaf(0.99f, v, czt);
        v = fmaxf(fmaf(0.01f, e, w), -85.0f);
        vmax = fmaxf(vmax, v);
        z *= 0.9875f;
        czt = c + z;
    }

    bool spiked = vmax >= 0.0f;
    unsigned long long bal = __ballot(spiked);
    if ((t & 63) == 0) m[t >> 6] = bal;
    __syncthreads();
    if (t == 0) sflags[blockIdx.x] = (m[0] | m[1] | m[2] | m[3]) ? 1 : 0;

    out[gid] = 0.0f;                             // overwritten by fallback if spikes
}

// ---------------- event-driven fallback (r3-proven), gated on sflags -------

__global__ __launch_bounds__(1024) void persist_kernel(const float* __restrict__ W,
                                                       const float* __restrict__ x0,
                                                       const float* __restrict__ V0,
                                                       const int* __restrict__ sflags,
                                                       float* __restrict__ zrec,
                                                       float* __restrict__ out) {
    const int t = threadIdx.x;
    const int lane = t & 63;

    bool spk = false;
#pragma unroll
    for (int i = 0; i < 4; ++i) spk |= (sflags[lane + 64 * i] != 0);
    if (!__any(spk)) return;                     // uniform exit: before any barrier

    __shared__ unsigned long long masks[2][16];
    __shared__ int cnt;
    __shared__ int list[4096];

    const int b = blockIdx.x;
    const int wv = t >> 6;
    const int n0 = t * 4;
    const size_t base = (size_t)b * NN + n0;

    float4 zr = *(const float4*)(zrec + base);
    float4 v  = *(const float4*)(V0 + base);
    float4 xx = *(const float4*)(x0 + base);
    float4 r  = {0.0f, 0.0f, 0.0f, 0.0f};

#pragma unroll 1
    for (int step = 0; step < 500; ++step) {
        const int p = step & 1;

        float z0 = zr.x + xx.x, z1 = zr.y + xx.y, z2 = zr.z + xx.z, z3 = zr.w + xx.w;

        float e0 = expf(v.x + 55.0f), e1 = expf(v.y + 55.0f);
        float e2 = expf(v.z + 55.0f), e3 = expf(v.w + 55.0f);
        v.x = fmaxf(fmaf(0.01f, -(v.x + 72.0f) + e0 + z0, v.x), -85.0f);
        v.y = fmaxf(fmaf(0.01f, -(v.y + 72.0f) + e1 + z1, v.y), -85.0f);
        v.z = fmaxf(fmaf(0.01f, -(v.z + 72.0f) + e2 + z2, v.z), -85.0f);
        v.w = fmaxf(fmaf(0.01f, -(v.w + 72.0f) + e3 + z3, v.w), -85.0f);

        bool s0 = v.x >= 0.0f, s1 = v.y >= 0.0f, s2 = v.z >= 0.0f, s3 = v.w >= 0.0f;
        if (s0) { v.x = -72.0f; r.x += 10.0f; }
        if (s1) { v.y = -72.0f; r.y += 10.0f; }
        if (s2) { v.z = -72.0f; r.z += 10.0f; }
        if (s3) { v.w = -72.0f; r.w += 10.0f; }

        zr.x *= 0.9875f; zr.y *= 0.9875f; zr.z *= 0.9875f; zr.w *= 0.9875f;

        bool any = s0 | s1 | s2 | s3;
        unsigned long long bal = __ballot(any);
        if (lane == 0) masks[p][wv] = bal;
        __syncthreads();

        unsigned long long tot = 0;
#pragma unroll
        for (int i = 0; i < 16; ++i) tot |= masks[p][i];

        if (tot != 0) {
            if (t == 0) cnt = 0;
            __syncthreads();
            int k = (int)s0 + (int)s1 + (int)s2 + (int)s3;
            if (k) {
                int pos = atomicAdd(&cnt, k);
                if (s0) list[pos++] = n0 + 0;
                if (s1) list[pos++] = n0 + 1;
                if (s2) list[pos++] = n0 + 2;
                if (s3) list[pos++] = n0 + 3;
            }
            __syncthreads();
            int mcnt = cnt;
            for (int s = 0; s < mcnt; ++s) {
                int j = list[s];
                zr.x += 0.125f * W[(size_t)(n0 + 0) * NN + j];
                zr.y += 0.125f * W[(size_t)(n0 + 1) * NN + j];
                zr.z += 0.125f * W[(size_t)(n0 + 2) * NN + j];
                zr.w += 0.125f * W[(size_t)(n0 + 3) * NN + j];
            }
        }
    }

    float4 o = {r.x * 0.002f, r.y * 0.002f, r.z * 0.002f, r.w * 0.002f};
    *(float4*)(out + base) = o;
}

extern "C" void kernel_launch(void* const* d_in, const int* in_sizes, int n_in,
                              void* d_out, int out_size, void* d_ws, size_t ws_size,
                              hipStream_t stream) {
    const float* W  = (const float*)d_in[0];
    const float* x0 = (const float*)d_in[1];
    const float* V0 = (const float*)d_in[2];
    const float* Y0 = (const float*)d_in[3];
    float* out  = (float*)d_out;
    float* ws   = (float*)d_ws;

    float* zrec = ws;                            // 65536 floats
    int* sflags = (int*)(ws + 65536);            // 256 ints

    spec_kernel<<<256, 256, 0, stream>>>(W, x0, V0, Y0, zrec, sflags, out);
    persist_kernel<<<16, 1024, 0, stream>>>(W, x0, V0, sflags, zrec, out);
}

// Round 7
// 98.026 us; speedup vs baseline: 164.7961x; 1.0396x over previous
//
#include <hip/hip_runtime.h>
#include <math.h>

// SpikingModel: 500-step EIF recurrent net, B=16, N=4096, fp32.
// Round-7: TWO dispatches; spec critical chain cut to 3 ops.
//   spec_kernel   : per-block Y0-row zero-scan -> z0 (0 common / gated dense dot).
//                   Barrier-free speculative integrator, chain fma -> v_exp -> fma
//                   (clamp REMOVED from chain; off-chain vmin latch routes any
//                   would-be clamp engagement to the exact fallback). Off-chain
//                   vmax latch detects spikes (conservative, NaN-safe).
//                   z0==0 specialization drops per-step z decay (block-uniform).
//   persist_kernel: r3-proven event-driven exact fallback, gated on flags,
//                   uniform early-exit when the speculation was valid + spike-free.
//
// ws layout: zrec[16][4096] floats @ 0 ; sflags[256] ints @ float-off 65536.

#define NN 4096

// ---------------- speculative integrator + self-gated Zrec(0) ---------------

__global__ __launch_bounds__(256) void spec_kernel(const float* __restrict__ W,
                                                   const float* __restrict__ x0,
                                                   const float* __restrict__ V0,
                                                   const float* __restrict__ Y0,
                                                   float* __restrict__ zrec,
                                                   int* __restrict__ sflags,
                                                   float* __restrict__ out) {
    __shared__ float yrow[NN];                   // 16 KB row stage (fallback only)
    __shared__ unsigned long long m[4];
    const int t = threadIdx.x;
    const int gid = blockIdx.x * 256 + t;        // 256 blocks x 256 = 65536
    const int b = blockIdx.x >> 4;               // 16 blocks per batch row
    const int n = gid & (NN - 1);

    // ---- Y0[b,:] zero-scan: 4 int4 per thread, bitwise OR (conservative) ---
    const int4* Yr4 = (const int4*)(Y0 + (size_t)b * NN);
    int4 o = {0, 0, 0, 0};
#pragma unroll
    for (int i = 0; i < 4; ++i) {
        int4 q = Yr4[i * 256 + t];
        o.x |= q.x; o.y |= q.y; o.z |= q.z; o.w |= q.w;
    }
    int ynz = __syncthreads_or(o.x | o.y | o.z | o.w);

    float z0 = 0.0f;
    if (ynz) {                                   // gated dense dot (never taken for
        const float4* Yr = (const float4*)(Y0 + (size_t)b * NN);  // zero Y0)
#pragma unroll
        for (int i = 0; i < 4; ++i)
            ((float4*)yrow)[i * 256 + t] = Yr[i * 256 + t];
        __syncthreads();
        const float4* Wr = (const float4*)(W + (size_t)n * NN);
        float4 a = {0.0f, 0.0f, 0.0f, 0.0f};
        for (int k = 0; k < NN / 4; ++k) {
            float4 y = ((const float4*)yrow)[k];
            float4 w = Wr[k];
            a.x = fmaf(y.x, w.x, a.x);
            a.y = fmaf(y.y, w.y, a.y);
            a.z = fmaf(y.z, w.z, a.z);
            a.w = fmaf(y.w, w.w, a.w);
        }
        z0 = (a.x + a.y) + (a.z + a.w);
    }
    zrec[gid] = z0;                              // fallback's Zrec(0); always written

    // ---- 500-step integration, 3-op critical chain -------------------------
    // v' = 0.99 v + 0.01 e^{v+55} + czt   (czt = 0.01(x+z) - 0.72)
    // chain: fma(v,L2E,K55) -> v_exp -> fma(0.01,e,w);  w = fma(0.99,v,czt),
    // vmax, vmin latches are off-chain. Clamp speculated away: vmin < -85
    // (or NaN) routes to exact fallback. vmax >= 0 routes spikes to fallback.
    float v = V0[gid];
    const float c = fmaf(0.01f, x0[gid], -0.72f);
    float vmax = v, vmin = v;
    const float L2E = 1.44269504088896f;
    const float K55 = 55.0f * 1.44269504088896f;

    if (z0 == 0.0f) {                            // common case: czt constant
#pragma unroll 10
        for (int s = 0; s < 500; ++s) {
            float e = __builtin_amdgcn_exp2f(fmaf(v, L2E, K55));
            float w = fmaf(0.99f, v, c);
            v = fmaf(0.01f, e, w);
            vmax = fmaxf(vmax, v);
            vmin = fminf(vmin, v);
        }
    } else {
        float z = z0 * 0.01f;
        float czt = c + z;
#pragma unroll 10
        for (int s = 0; s < 500; ++s) {
            float e = __builtin_amdgcn_exp2f(fmaf(v, L2E, K55));
            float w = fmaf(0.99f, v, czt);
            v = fmaf(0.01f, e, w);
            vmax = fmaxf(vmax, v);
            vmin = fminf(vmin, v);
            z *= 0.9875f;
            czt = c + z;
        }
    }

    // invalid speculation (clamp would have engaged / NaN) OR spike -> fallback
    bool fb = (vmax >= 0.0f) || !(vmin >= -85.0f);
    unsigned long long bal = __ballot(fb);
    if ((t & 63) == 0) m[t >> 6] = bal;
    __syncthreads();
    if (t == 0) sflags[blockIdx.x] = (m[0] | m[1] | m[2] | m[3]) ? 1 : 0;

    out[gid] = 0.0f;                             // overwritten by fallback if set
}

// ---------------- event-driven exact fallback (r3-proven), gated -----------

__global__ __launch_bounds__(1024) void persist_kernel(const float* __restrict__ W,
                                                       const float* __restrict__ x0,
                                                       const float* __restrict__ V0,
                                                       const int* __restrict__ sflags,
                                                       float* __restrict__ zrec,
                                                       float* __restrict__ out) {
    const int t = threadIdx.x;
    const int lane = t & 63;

    bool spk = false;
#pragma unroll
    for (int i = 0; i < 4; ++i) spk |= (sflags[lane + 64 * i] != 0);
    if (!__any(spk)) return;                     // uniform exit: before any barrier

    __shared__ unsigned long long masks[2][16];
    __shared__ int cnt;
    __shared__ int list[4096];

    const int b = blockIdx.x;
    const int wv = t >> 6;
    const int n0 = t * 4;
    const size_t base = (size_t)b * NN + n0;

    float4 zr = *(const float4*)(zrec + base);
    float4 v  = *(const float4*)(V0 + base);
    float4 xx = *(const float4*)(x0 + base);
    float4 r  = {0.0f, 0.0f, 0.0f, 0.0f};

#pragma unroll 1
    for (int step = 0; step < 500; ++step) {
        const int p = step & 1;

        float z0 = zr.x + xx.x, z1 = zr.y + xx.y, z2 = zr.z + xx.z, z3 = zr.w + xx.w;

        float e0 = expf(v.x + 55.0f), e1 = expf(v.y + 55.0f);
        float e2 = expf(v.z + 55.0f), e3 = expf(v.w + 55.0f);
        v.x = fmaxf(fmaf(0.01f, -(v.x + 72.0f) + e0 + z0, v.x), -85.0f);
        v.y = fmaxf(fmaf(0.01f, -(v.y + 72.0f) + e1 + z1, v.y), -85.0f);
        v.z = fmaxf(fmaf(0.01f, -(v.z + 72.0f) + e2 + z2, v.z), -85.0f);
        v.w = fmaxf(fmaf(0.01f, -(v.w + 72.0f) + e3 + z3, v.w), -85.0f);

        bool s0 = v.x >= 0.0f, s1 = v.y >= 0.0f, s2 = v.z >= 0.0f, s3 = v.w >= 0.0f;
        if (s0) { v.x = -72.0f; r.x += 10.0f; }
        if (s1) { v.y = -72.0f; r.y += 10.0f; }
        if (s2) { v.z = -72.0f; r.z += 10.0f; }
        if (s3) { v.w = -72.0f; r.w += 10.0f; }

        zr.x *= 0.9875f; zr.y *= 0.9875f; zr.z *= 0.9875f; zr.w *= 0.9875f;

        bool any = s0 | s1 | s2 | s3;
        unsigned long long bal = __ballot(any);
        if (lane == 0) masks[p][wv] = bal;
        __syncthreads();

        unsigned long long tot = 0;
#pragma unroll
        for (int i = 0; i < 16; ++i) tot |= masks[p][i];

        if (tot != 0) {
            if (t == 0) cnt = 0;
            __syncthreads();
            int k = (int)s0 + (int)s1 + (int)s2 + (int)s3;
            if (k) {
                int pos = atomicAdd(&cnt, k);
                if (s0) list[pos++] = n0 + 0;
                if (s1) list[pos++] = n0 + 1;
                if (s2) list[pos++] = n0 + 2;
                if (s3) list[pos++] = n0 + 3;
            }
            __syncthreads();
            int mcnt = cnt;
            for (int s = 0; s < mcnt; ++s) {
                int j = list[s];
                zr.x += 0.125f * W[(size_t)(n0 + 0) * NN + j];
                zr.y += 0.125f * W[(size_t)(n0 + 1) * NN + j];
                zr.z += 0.125f * W[(size_t)(n0 + 2) * NN + j];
                zr.w += 0.125f * W[(size_t)(n0 + 3) * NN + j];
            }
        }
    }

    float4 o = {r.x * 0.002f, r.y * 0.002f, r.z * 0.002f, r.w * 0.002f};
    *(float4*)(out + base) = o;
}

extern "C" void kernel_launch(void* const* d_in, const int* in_sizes, int n_in,
                              void* d_out, int out_size, void* d_ws, size_t ws_size,
                              hipStream_t stream) {
    const float* W  = (const float*)d_in[0];
    const float* x0 = (const float*)d_in[1];
    const float* V0 = (const float*)d_in[2];
    const float* Y0 = (const float*)d_in[3];
    float* out  = (float*)d_out;
    float* ws   = (float*)d_ws;

    float* zrec = ws;                            // 65536 floats
    int* sflags = (int*)(ws + 65536);            // 256 ints

    spec_kernel<<<256, 256, 0, stream>>>(W, x0, V0, Y0, zrec, sflags, out);
    persist_kernel<<<16, 1024, 0, stream>>>(W, x0, V0, sflags, zrec, out);
}